// Round 1
// baseline (7260.398 us; speedup 1.0000x reference)
//
#include <hip/hip_runtime.h>
#include <hip/hip_bf16.h>
#include <cstddef>

// Problem constants
#define PP 32       // particles
#define BB 64       // batch
#define TT 100      // time steps
#define WW 50       // window
#define EE 64       // embed
#define HH 256      // hidden
// ALPHA = 0.5, (1-ALPHA)/P = 0.015625

__device__ __forceinline__ float sigm(float x) { return 1.0f / (1.0f + expf(-x)); }
__device__ __forceinline__ float softplusf(float x) {
    // stable: max(x,0) + log1p(exp(-|x|))  (matches jax.nn.softplus)
    return fmaxf(x, 0.0f) + log1pf(expf(-fabsf(x)));
}

// ---------------------------------------------------------------------------
// Prologue: emb[b,t,:] = relu(prev_window[b,t,:] @ W_act + b_act)  -> embT[(t*64+b)*64+e]
// also xobs[t*64+b] = emb . W_obs[256:320] + b_obs
// grid: 1600 blocks x 256 threads (4 (b,t) pairs per block, one wave each)
// ---------------------------------------------------------------------------
__global__ __launch_bounds__(256) void k_emb(
    const float* __restrict__ pw, const float* __restrict__ w_act,
    const float* __restrict__ b_act, const float* __restrict__ w_obs,
    const float* __restrict__ b_obs, float* __restrict__ embT,
    float* __restrict__ xobs)
{
    int tid = threadIdx.x;
    int sub = tid >> 6;          // 0..3 (one wave per (b,t))
    int e   = tid & 63;
    int bt  = blockIdx.x * 4 + sub;   // = b*100 + t
    int b = bt / TT, t = bt % TT;

    __shared__ float pws[4][WW + 2];
    if (e < WW) pws[sub][e] = pw[(size_t)bt * WW + e];
    __syncthreads();

    float acc = b_act[e];
    #pragma unroll 5
    for (int w = 0; w < WW; ++w) acc += pws[sub][w] * w_act[w * EE + e];
    float r = fmaxf(acc, 0.0f);
    embT[((size_t)t * BB + b) * EE + e] = r;

    float xv = r * w_obs[HH + e];
    #pragma unroll
    for (int d = 1; d < 64; d <<= 1) xv += __shfl_xor(xv, d);
    if (e == 0) xobs[t * BB + b] = xv + b_obs[0];
}

// ---------------------------------------------------------------------------
// S1: fused recurrent GEMM + LSTM elementwise.
// gates[row, g*256+hcol] = sum_k h_in[row,k]*W_hh[k, g*256+hcol]
//                        + sum_e embT_t[b,e]*W_ih[e, g*256+hcol] + b_ih + b_hh
// then c1 = sig(f)*c + sig(i)*tanh(g) + softplus(var)*eps ; h1 = sig(o)*tanh(c1)
// grid: (32 row-tiles, 8 h-tiles), 256 threads.
// Per block: 64 rows x 32 hcols x 5 gates.  Thread: 4 rows x 2 hcols x 5 gates.
// ---------------------------------------------------------------------------
__global__ __launch_bounds__(256) void s1_kernel(
    const float* __restrict__ h_in, const float* __restrict__ c_in,
    const float* __restrict__ embT_t,
    const float* __restrict__ W_hh, const float* __restrict__ W_ih,
    const float* __restrict__ b_ih, const float* __restrict__ b_hh,
    const float* __restrict__ eps_t,
    float* __restrict__ h1o, float* __restrict__ c1o)
{
    __shared__ float lA[32][64];    // [k][row]
    __shared__ float lB[32][160];   // [k][g*32+hc]

    int tid  = threadIdx.x;
    int row0 = blockIdx.x * 64;
    int ht   = blockIdx.y;

    float acc[5][4][2];
    #pragma unroll
    for (int g = 0; g < 5; ++g)
        #pragma unroll
        for (int r = 0; r < 4; ++r)
            #pragma unroll
            for (int c = 0; c < 2; ++c) acc[g][r][c] = 0.0f;

    int rg  = tid & 15;   // row group: rows rg*4 .. rg*4+3
    int hcp = tid >> 4;   // hcol pair: cols hcp*2, hcp*2+1

    for (int kc = 0; kc < 10; ++kc) {     // 8 chunks of h (K=256) + 2 chunks of x (K=64)
        // ---- stage A (rows x 32 k), transposed into lA[k][row]
        #pragma unroll
        for (int it = 0; it < 2; ++it) {
            int q  = tid + it * 256;      // 0..511
            int r  = q >> 3;              // 0..63
            int kq = q & 7;               // 0..7
            float4 v;
            if (kc < 8) v = *(const float4*)&h_in[(size_t)(row0 + r) * HH + kc * 32 + kq * 4];
            else        v = *(const float4*)&embT_t[(size_t)r * EE + (kc - 8) * 32 + kq * 4];
            lA[kq * 4 + 0][r] = v.x;
            lA[kq * 4 + 1][r] = v.y;
            lA[kq * 4 + 2][r] = v.z;
            lA[kq * 4 + 3][r] = v.w;
        }
        // ---- stage B (32 k x 160 cols)
        #pragma unroll
        for (int s = 0; s < 5; ++s) {
            int q    = tid + s * 256;     // 0..1279
            int k    = q / 40;
            int rem  = q - k * 40;
            int gg   = rem >> 3;          // gate 0..4
            int quad = rem & 7;
            int col  = gg * HH + ht * 32 + quad * 4;
            float4 v;
            if (kc < 8) v = *(const float4*)&W_hh[(size_t)(kc * 32 + k) * 1280 + col];
            else        v = *(const float4*)&W_ih[(size_t)((kc - 8) * 32 + k) * 1280 + col];
            *(float4*)&lB[k][gg * 32 + quad * 4] = v;
        }
        __syncthreads();

        #pragma unroll 8
        for (int k = 0; k < 32; ++k) {
            float4 a = *(const float4*)&lA[k][rg * 4];
            #pragma unroll
            for (int g = 0; g < 5; ++g) {
                float2 bb = *(const float2*)&lB[k][g * 32 + hcp * 2];
                acc[g][0][0] += a.x * bb.x;  acc[g][0][1] += a.x * bb.y;
                acc[g][1][0] += a.y * bb.x;  acc[g][1][1] += a.y * bb.y;
                acc[g][2][0] += a.z * bb.x;  acc[g][2][1] += a.z * bb.y;
                acc[g][3][0] += a.w * bb.x;  acc[g][3][1] += a.w * bb.y;
            }
        }
        __syncthreads();
    }

    // ---- epilogue: biases + LSTM elementwise
    #pragma unroll
    for (int rr = 0; rr < 4; ++rr) {
        int row = row0 + rg * 4 + rr;
        #pragma unroll
        for (int cc = 0; cc < 2; ++cc) {
            int hcol = ht * 32 + hcp * 2 + cc;
            float gi = acc[0][rr][cc] + b_ih[0 * HH + hcol] + b_hh[0 * HH + hcol];
            float gf = acc[1][rr][cc] + b_ih[1 * HH + hcol] + b_hh[1 * HH + hcol];
            float gg = acc[2][rr][cc] + b_ih[2 * HH + hcol] + b_hh[2 * HH + hcol];
            float go = acc[3][rr][cc] + b_ih[3 * HH + hcol] + b_hh[3 * HH + hcol];
            float gv = acc[4][rr][cc] + b_ih[4 * HH + hcol] + b_hh[4 * HH + hcol];

            size_t off = (size_t)row * HH + hcol;
            float cp  = c_in[off];
            float mu  = sigm(gf) * cp + sigm(gi) * tanhf(gg);
            float c1v = mu + softplusf(gv) * eps_t[off];
            float h1v = sigm(go) * tanhf(c1v);
            c1o[off] = c1v;
            h1o[off] = h1v;
        }
    }
}

// ---------------------------------------------------------------------------
// S2: per batch-column b: logpdf, log-softmax over P, gumbel-argmax resample,
// gather h/c, emit pf_out and y_out.  grid: 64 blocks x 256 threads.
// ---------------------------------------------------------------------------
__global__ __launch_bounds__(256) void s2_kernel(
    const float* __restrict__ h1, const float* __restrict__ c1,
    const float* __restrict__ xobs_t, const float* __restrict__ g_t,
    const float* __restrict__ w_obs, const float* __restrict__ w_lab,
    const float* __restrict__ b_lab,
    float* __restrict__ p_buf, int first,
    float* __restrict__ h_out, float* __restrict__ c_out,
    float* __restrict__ y_out_t, float* __restrict__ pf_out_t)
{
    int b   = blockIdx.x;
    int tid = threadIdx.x;

    __shared__ float gt[PP][PP + 1];  // padded: avoid 32-way bank conflict
    __shared__ float lg[PP];          // p_prev + logpdf
    __shared__ float w1s[PP];
    __shared__ float lgt[PP];         // logits
    __shared__ int   idxs[PP];
    __shared__ float pnew[PP];
    __shared__ float dpart[PP];

    // stage gumbel tile (32x32)
    {
        float4 v = ((const float4*)(g_t + (size_t)b * 1024))[tid];
        int p = tid >> 3, j0 = (tid & 7) * 4;
        gt[p][j0 + 0] = v.x; gt[p][j0 + 1] = v.y;
        gt[p][j0 + 2] = v.z; gt[p][j0 + 3] = v.w;
    }

    // phase 1: logpdf[p] = h1[p*64+b,:] . w_obs[0:256]  (+ xobs + p_prev)
    int p = tid >> 3, l8 = tid & 7;
    {
        const float* hrow = h1 + ((size_t)(p * BB + b)) * HH;
        float s = 0.0f;
        #pragma unroll 8
        for (int j = 0; j < 32; ++j) s += hrow[j * 8 + l8] * w_obs[j * 8 + l8];
        s += __shfl_xor(s, 1); s += __shfl_xor(s, 2); s += __shfl_xor(s, 4);
        if (l8 == 0) {
            float pprev = first ? -3.4657359027997265f : p_buf[p * BB + b];
            lg[p] = pprev + s + xobs_t[b];
        }
    }
    __syncthreads();

    // phase 2: p1 = log_softmax over P; w1 = exp(p1); logits = log(0.5*w1 + 1/64)
    if (tid < 32) {
        float v = lg[tid];
        float m = v;
        #pragma unroll
        for (int d = 1; d < 32; d <<= 1) m = fmaxf(m, __shfl_xor(m, d));
        float e = expf(v - m), se = e;
        #pragma unroll
        for (int d = 1; d < 32; d <<= 1) se += __shfl_xor(se, d);
        float l1 = v - m - logf(se);
        float w1 = expf(l1);
        w1s[tid] = w1;
        lgt[tid] = logf(0.5f * w1 + 0.015625f);
    }
    __syncthreads();

    // phase 3: idx[p] = argmax_j(logits[j] + g[b,p,j]); new weights; p_new
    if (tid < 32) {
        int p2 = tid;
        float best = -INFINITY; int bi = 0;
        #pragma unroll 8
        for (int j = 0; j < 32; ++j) {
            float val = lgt[j] + gt[p2][j];
            if (val > best) { best = val; bi = j; }   // strict >: first max, like jnp.argmax
        }
        idxs[p2] = bi;
        float wv = w1s[bi];
        wv = wv / (0.5f * wv + 0.015625f);
        float lw = logf(wv);
        float m2 = lw;
        #pragma unroll
        for (int d = 1; d < 32; d <<= 1) m2 = fmaxf(m2, __shfl_xor(m2, d));
        float e2 = expf(lw - m2), s2 = e2;
        #pragma unroll
        for (int d = 1; d < 32; d <<= 1) s2 += __shfl_xor(s2, d);
        float pn = lw - m2 - logf(s2);
        pnew[p2] = pn;
        p_buf[p2 * BB + b] = pn;
    }
    __syncthreads();

    // phase 4: gather resampled h,c
    for (int pp = 0; pp < PP; ++pp) {
        int src = idxs[pp];
        size_t so = ((size_t)(src * BB + b)) * HH + tid;
        size_t dof = ((size_t)(pp * BB + b)) * HH + tid;
        h_out[dof] = h1[so];
        c_out[dof] = c1[so];
    }
    __syncthreads();

    // phase 5: d[p] = h_new[p,b,:] . W_lab ; pf_out ; y_out
    {
        const float* hr2 = h_out + ((size_t)(p * BB + b)) * HH;
        float ds = 0.0f;
        #pragma unroll 8
        for (int j = 0; j < 32; ++j) ds += hr2[j * 8 + l8] * w_lab[j * 8 + l8];
        ds += __shfl_xor(ds, 1); ds += __shfl_xor(ds, 2); ds += __shfl_xor(ds, 4);
        if (l8 == 0) dpart[p] = ds;
    }
    __syncthreads();
    if (tid < 32) {
        float dd = dpart[tid];
        float bl = b_lab[0];
        pf_out_t[tid * BB + b] = 1.0f / (1.0f + expf(-(dd + bl)));
        float contrib = expf(pnew[tid]) * dd;
        #pragma unroll
        for (int d = 1; d < 32; d <<= 1) contrib += __shfl_xor(contrib, d);
        if (tid == 0) y_out_t[b] = 1.0f / (1.0f + expf(-(contrib + bl)));
    }
}

// ---------------------------------------------------------------------------
extern "C" void kernel_launch(void* const* d_in, const int* in_sizes, int n_in,
                              void* d_out, int out_size, void* d_ws, size_t ws_size,
                              hipStream_t stream)
{
    const float* prev_window = (const float*)d_in[0];   // (B,T,W)
    const float* h0    = (const float*)d_in[1];         // (P*B,H)
    const float* c0    = (const float*)d_in[2];
    const float* eps   = (const float*)d_in[3];         // (T,P*B,H)
    const float* gum   = (const float*)d_in[4];         // (T,B,P,P)
    const float* W_act = (const float*)d_in[5];
    const float* b_act = (const float*)d_in[6];
    const float* W_ih  = (const float*)d_in[7];
    const float* b_ih  = (const float*)d_in[8];
    const float* W_hh  = (const float*)d_in[9];
    const float* b_hh  = (const float*)d_in[10];
    const float* W_obs = (const float*)d_in[11];        // (320,1)
    const float* b_obs = (const float*)d_in[12];
    const float* W_lab = (const float*)d_in[13];        // (256,1)
    const float* b_lab = (const float*)d_in[14];

    float* out = (float*)d_out;       // [T*B] y_out then [T*P*B] pf_out
    float* ws  = (float*)d_ws;

    float* embT = ws;                         // T*B*E      = 409600
    float* xobs = embT + 409600;              // T*B        = 6400
    float* h1   = xobs + 6400;                // 2048*256   = 524288
    float* c1   = h1 + 524288;
    float* hc   = c1 + 524288;
    float* cc   = hc + 524288;
    float* pb   = cc + 524288;                // 2048

    k_emb<<<1600, 256, 0, stream>>>(prev_window, W_act, b_act, W_obs, b_obs, embT, xobs);

    for (int t = 0; t < TT; ++t) {
        const float* hi = (t == 0) ? h0 : hc;
        const float* ci = (t == 0) ? c0 : cc;
        s1_kernel<<<dim3(32, 8), 256, 0, stream>>>(
            hi, ci, embT + (size_t)t * BB * EE,
            W_hh, W_ih, b_ih, b_hh,
            eps + (size_t)t * PP * BB * HH,
            h1, c1);
        s2_kernel<<<64, 256, 0, stream>>>(
            h1, c1, xobs + t * BB, gum + (size_t)t * BB * PP * PP,
            W_obs, W_lab, b_lab,
            pb, (t == 0) ? 1 : 0,
            hc, cc,
            out + (size_t)t * BB,
            out + (size_t)TT * BB + (size_t)t * PP * BB);
    }
}

// Round 2
// 4198.743 us; speedup vs baseline: 1.7292x; 1.7292x over previous
//
#include <hip/hip_runtime.h>
#include <hip/hip_bf16.h>
#include <cstddef>

// Problem constants
#define PP 32       // particles
#define BB 64       // batch
#define TT 100      // time steps
#define WW 50       // window
#define EE 64       // embed
#define HH 256      // hidden
// ALPHA = 0.5, (1-ALPHA)/P = 0.015625

__device__ __forceinline__ float sigm(float x) { return 1.0f / (1.0f + expf(-x)); }
__device__ __forceinline__ float softplusf(float x) {
    return fmaxf(x, 0.0f) + log1pf(expf(-fabsf(x)));
}

// ---------------------------------------------------------------------------
// Prologue A: emb[t,b,:] = relu(prev_window[b,t,:] @ W_act + b_act)
// also xobs[t*64+b] = emb . W_obs[256:320] + b_obs
// ---------------------------------------------------------------------------
__global__ __launch_bounds__(256) void k_emb(
    const float* __restrict__ pw, const float* __restrict__ w_act,
    const float* __restrict__ b_act, const float* __restrict__ w_obs,
    const float* __restrict__ b_obs, float* __restrict__ embT,
    float* __restrict__ xobs)
{
    int tid = threadIdx.x;
    int sub = tid >> 6;          // 0..3 (one wave per (b,t))
    int e   = tid & 63;
    int bt  = blockIdx.x * 4 + sub;   // = b*100 + t
    int b = bt / TT, t = bt % TT;

    __shared__ float pws[4][WW + 2];
    if (e < WW) pws[sub][e] = pw[(size_t)bt * WW + e];
    __syncthreads();

    float acc = b_act[e];
    #pragma unroll 5
    for (int w = 0; w < WW; ++w) acc += pws[sub][w] * w_act[w * EE + e];
    float r = fmaxf(acc, 0.0f);
    embT[((size_t)t * BB + b) * EE + e] = r;

    float xv = r * w_obs[HH + e];
    #pragma unroll
    for (int d = 1; d < 64; d <<= 1) xv += __shfl_xor(xv, d);
    if (e == 0) xobs[t * BB + b] = xv + b_obs[0];
}

// ---------------------------------------------------------------------------
// Prologue B: pack weights for scalar-broadcast GEMM.
// Wp[((ht*320 + k)*160) + lh*5 + g] = W[k][g*256 + ht*32 + lh]
//   where W = rows 0..255 from W_hh, rows 256..319 from W_ih.
// ---------------------------------------------------------------------------
__global__ __launch_bounds__(256) void k_pack(
    const float* __restrict__ W_ih, const float* __restrict__ W_hh,
    float* __restrict__ Wp)
{
    int i = blockIdx.x * 256 + threadIdx.x;   // 409600 total
    int ht  = i / 51200;
    int rem = i - ht * 51200;
    int k   = rem / 160;
    int c   = rem - k * 160;
    int lh  = c / 5, g = c - lh * 5;
    int col = g * HH + ht * 32 + lh;
    float v = (k < HH) ? W_hh[(size_t)k * 1280 + col]
                       : W_ih[(size_t)(k - HH) * 1280 + col];
    Wp[i] = v;
}

// ---------------------------------------------------------------------------
// S1: recurrent GEMM + LSTM elementwise + partial output dots.
// grid (32 particles, 8 h-tiles) x 512 threads (8 waves).
// Block: 64 rows (lane = row = batch b) x 160 gate-cols (32 hcols x 5 gates).
// Wave w handles packed cols [w*20, w*20+20) = hcols [w*4, w*4+4) x 5 gates.
// B weights are wave-uniform -> scalar loads (SMEM pipe).
// A gathered on read via gidx (resampling fold).
// ---------------------------------------------------------------------------
__global__ __launch_bounds__(512) void s1_kernel(
    const float* __restrict__ h_in, const float* __restrict__ c_in,
    const int* __restrict__ gidx,            // null at t=0 (identity)
    const float* __restrict__ embT_t,
    const float* __restrict__ Wp,
    const float* __restrict__ b_ih, const float* __restrict__ b_hh,
    const float* __restrict__ w_obs, const float* __restrict__ w_lab,
    const float* __restrict__ eps_t,
    float* __restrict__ h1o, float* __restrict__ c1o,
    float* __restrict__ dpo, float* __restrict__ dpl)   // [8][2048] each
{
    __shared__ float lA[32][72];       // [k][row], stride 72 -> 2-way-free reads
    __shared__ int   lidx[64];
    __shared__ float ldot[8][64][2];

    int tid  = threadIdx.x;
    int row0 = blockIdx.x * 64;        // particle p = blockIdx.x
    int ht   = blockIdx.y;
    int lane = tid & 63;
    int wu   = __builtin_amdgcn_readfirstlane(tid >> 6);   // wave id, SGPR

    if (tid < 64) lidx[tid] = gidx ? gidx[row0 + tid] : (row0 + tid);

    float acc[20];
    #pragma unroll
    for (int c = 0; c < 20; ++c) acc[c] = 0.0f;

    int r  = tid >> 3;     // staging row 0..63
    int kq = tid & 7;      // staging k-quad 0..7

    // uniform base for this (ht, wave)'s packed B columns
    const float* __restrict__ wbase = Wp + (size_t)ht * 320 * 160 + wu * 20;

    __syncthreads();

    for (int kc = 0; kc < 10; ++kc) {
        // ---- stage A chunk (64 rows x 32 k), gather-on-read
        {
            float4 v;
            if (kc < 8) {
                int src = lidx[r];
                v = *(const float4*)&h_in[(size_t)src * HH + kc * 32 + kq * 4];
            } else {
                v = *(const float4*)&embT_t[(size_t)r * EE + (kc - 8) * 32 + kq * 4];
            }
            lA[kq * 4 + 0][r] = v.x;
            lA[kq * 4 + 1][r] = v.y;
            lA[kq * 4 + 2][r] = v.z;
            lA[kq * 4 + 3][r] = v.w;
        }
        __syncthreads();

        const float* wk = wbase + kc * 32 * 160;
        #pragma unroll
        for (int k = 0; k < 32; ++k) {
            float a = lA[k][lane];
            const float* bp = wk + k * 160;
            float4 b0 = *(const float4*)(bp);
            float4 b1 = *(const float4*)(bp + 4);
            float4 b2 = *(const float4*)(bp + 8);
            float4 b3 = *(const float4*)(bp + 12);
            float4 b4 = *(const float4*)(bp + 16);
            acc[ 0] += a * b0.x; acc[ 1] += a * b0.y; acc[ 2] += a * b0.z; acc[ 3] += a * b0.w;
            acc[ 4] += a * b1.x; acc[ 5] += a * b1.y; acc[ 6] += a * b1.z; acc[ 7] += a * b1.w;
            acc[ 8] += a * b2.x; acc[ 9] += a * b2.y; acc[10] += a * b2.z; acc[11] += a * b2.w;
            acc[12] += a * b3.x; acc[13] += a * b3.y; acc[14] += a * b3.z; acc[15] += a * b3.w;
            acc[16] += a * b4.x; acc[17] += a * b4.y; acc[18] += a * b4.z; acc[19] += a * b4.w;
        }
        __syncthreads();
    }

    // ---- epilogue: thread (wave wu, lane=row) owns hcols ht*32+wu*4 .. +4
    int row    = row0 + lane;
    int srcrow = lidx[lane];
    float pdo = 0.0f, pdl = 0.0f;

    int hc0 = ht * 32 + wu * 4;
    float4 cin  = *(const float4*)&c_in[(size_t)srcrow * HH + hc0];
    float4 epsv = *(const float4*)&eps_t[(size_t)row * HH + hc0];
    float cps[4] = {cin.x, cin.y, cin.z, cin.w};
    float eps4[4] = {epsv.x, epsv.y, epsv.z, epsv.w};
    float c1v4[4], h1v4[4];

    #pragma unroll
    for (int l = 0; l < 4; ++l) {
        int hcol = hc0 + l;
        float gi = acc[l * 5 + 0] + b_ih[0 * HH + hcol] + b_hh[0 * HH + hcol];
        float gf = acc[l * 5 + 1] + b_ih[1 * HH + hcol] + b_hh[1 * HH + hcol];
        float gg = acc[l * 5 + 2] + b_ih[2 * HH + hcol] + b_hh[2 * HH + hcol];
        float go = acc[l * 5 + 3] + b_ih[3 * HH + hcol] + b_hh[3 * HH + hcol];
        float gv = acc[l * 5 + 4] + b_ih[4 * HH + hcol] + b_hh[4 * HH + hcol];

        float mu  = sigm(gf) * cps[l] + sigm(gi) * tanhf(gg);
        float c1v = mu + softplusf(gv) * eps4[l];
        float h1v = sigm(go) * tanhf(c1v);
        c1v4[l] = c1v;
        h1v4[l] = h1v;
        pdo += h1v * w_obs[hcol];
        pdl += h1v * w_lab[hcol];
    }
    *(float4*)&c1o[(size_t)row * HH + hc0] = *(float4*)c1v4;
    *(float4*)&h1o[(size_t)row * HH + hc0] = *(float4*)h1v4;

    ldot[tid >> 6][lane][0] = pdo;
    ldot[tid >> 6][lane][1] = pdl;
    __syncthreads();
    if (tid < 64) {
        float so = 0.0f, sl = 0.0f;
        #pragma unroll
        for (int ww = 0; ww < 8; ++ww) { so += ldot[ww][tid][0]; sl += ldot[ww][tid][1]; }
        dpo[ht * 2048 + row0 + tid] = so;
        dpl[ht * 2048 + row0 + tid] = sl;
    }
}

// ---------------------------------------------------------------------------
// S2: per batch-column b, 1 wave: log-softmax over P, gumbel-argmax,
// write gidx for next step's gather-on-read, emit pf_out and y_out.
// ---------------------------------------------------------------------------
__global__ __launch_bounds__(64) void s2_kernel(
    const float* __restrict__ dpo, const float* __restrict__ dpl,
    const float* __restrict__ xobs_t, const float* __restrict__ g_t,
    const float* __restrict__ b_lab,
    float* __restrict__ p_buf, int first,
    int* __restrict__ gidx_next,
    float* __restrict__ y_out_t, float* __restrict__ pf_out_t)
{
    int b   = blockIdx.x;
    int tid = threadIdx.x;

    __shared__ float gt[PP][PP + 1];
    __shared__ float lgt[PP];
    __shared__ float w1s[PP];

    for (int i = tid; i < 256; i += 64) {
        float4 v = ((const float4*)(g_t + (size_t)b * 1024))[i];
        int p = i >> 3, j0 = (i & 7) * 4;
        gt[p][j0 + 0] = v.x; gt[p][j0 + 1] = v.y;
        gt[p][j0 + 2] = v.z; gt[p][j0 + 3] = v.w;
    }
    __syncthreads();

    if (tid < 32) {
        int p = tid;
        float dob = 0.0f;
        #pragma unroll
        for (int h = 0; h < 8; ++h) dob += dpo[h * 2048 + p * BB + b];
        float pprev = first ? -3.4657359027997265f : p_buf[p * BB + b];
        float v = pprev + dob + xobs_t[b];

        float m = v;
        #pragma unroll
        for (int d = 1; d < 32; d <<= 1) m = fmaxf(m, __shfl_xor(m, d));
        float e = expf(v - m), se = e;
        #pragma unroll
        for (int d = 1; d < 32; d <<= 1) se += __shfl_xor(se, d);
        float l1 = v - m - logf(se);
        float w1 = expf(l1);
        w1s[p] = w1;
        lgt[p] = logf(0.5f * w1 + 0.015625f);
    }
    __syncthreads();

    if (tid < 32) {
        int p = tid;
        float best = -INFINITY; int bi = 0;
        #pragma unroll 8
        for (int j = 0; j < 32; ++j) {
            float val = lgt[j] + gt[p][j];
            if (val > best) { best = val; bi = j; }   // first max, like jnp.argmax
        }
        gidx_next[p * BB + b] = bi * BB + b;

        float wv = w1s[bi];
        wv = wv / (0.5f * wv + 0.015625f);
        float lw = logf(wv);
        float m2 = lw;
        #pragma unroll
        for (int d = 1; d < 32; d <<= 1) m2 = fmaxf(m2, __shfl_xor(m2, d));
        float e2 = expf(lw - m2), s2 = e2;
        #pragma unroll
        for (int d = 1; d < 32; d <<= 1) s2 += __shfl_xor(s2, d);
        float pn = lw - m2 - logf(s2);
        p_buf[p * BB + b] = pn;

        float dlb = 0.0f;
        int grow = bi * BB + b;
        #pragma unroll
        for (int h = 0; h < 8; ++h) dlb += dpl[h * 2048 + grow];
        float blv = b_lab[0];
        pf_out_t[p * BB + b] = 1.0f / (1.0f + expf(-(dlb + blv)));

        float contrib = expf(pn) * dlb;
        #pragma unroll
        for (int d = 1; d < 32; d <<= 1) contrib += __shfl_xor(contrib, d);
        if (p == 0) y_out_t[b] = 1.0f / (1.0f + expf(-(contrib + blv)));
    }
}

// ---------------------------------------------------------------------------
extern "C" void kernel_launch(void* const* d_in, const int* in_sizes, int n_in,
                              void* d_out, int out_size, void* d_ws, size_t ws_size,
                              hipStream_t stream)
{
    const float* prev_window = (const float*)d_in[0];   // (B,T,W)
    const float* h0    = (const float*)d_in[1];         // (P*B,H)
    const float* c0    = (const float*)d_in[2];
    const float* eps   = (const float*)d_in[3];         // (T,P*B,H)
    const float* gum   = (const float*)d_in[4];         // (T,B,P,P)
    const float* W_act = (const float*)d_in[5];
    const float* b_act = (const float*)d_in[6];
    const float* W_ih  = (const float*)d_in[7];
    const float* b_ih  = (const float*)d_in[8];
    const float* W_hh  = (const float*)d_in[9];
    const float* b_hh  = (const float*)d_in[10];
    const float* W_obs = (const float*)d_in[11];        // (320,1)
    const float* b_obs = (const float*)d_in[12];
    const float* W_lab = (const float*)d_in[13];        // (256,1)
    const float* b_lab = (const float*)d_in[14];

    float* out = (float*)d_out;       // [T*B] y_out then [T*P*B] pf_out
    float* ws  = (float*)d_ws;

    float* embT = ws;                         // 409600
    float* xobs = embT + 409600;              // 6400
    float* Wp   = xobs + 6400;                // 409600
    float* h1a  = Wp + 409600;                // 524288
    float* c1a  = h1a + 524288;
    float* h1b  = c1a + 524288;
    float* c1b  = h1b + 524288;
    float* pb   = c1b + 524288;               // 2048
    int*   gidx = (int*)(pb + 2048);          // 2048
    float* dpo  = (float*)(gidx + 2048);      // 16384
    float* dpl  = dpo + 16384;                // 16384

    k_emb<<<1600, 256, 0, stream>>>(prev_window, W_act, b_act, W_obs, b_obs, embT, xobs);
    k_pack<<<1600, 256, 0, stream>>>(W_ih, W_hh, Wp);

    for (int t = 0; t < TT; ++t) {
        const float* hi = (t == 0) ? h0 : ((t & 1) ? h1a : h1b);
        const float* ci = (t == 0) ? c0 : ((t & 1) ? c1a : c1b);
        float* ho = (t & 1) ? h1b : h1a;
        float* co = (t & 1) ? c1b : c1a;
        const int* gi = (t == 0) ? nullptr : gidx;

        s1_kernel<<<dim3(32, 8), 512, 0, stream>>>(
            hi, ci, gi, embT + (size_t)t * BB * EE,
            Wp, b_ih, b_hh, W_obs, W_lab,
            eps + (size_t)t * PP * BB * HH,
            ho, co, dpo, dpl);

        s2_kernel<<<64, 64, 0, stream>>>(
            dpo, dpl, xobs + t * BB, gum + (size_t)t * BB * PP * PP,
            b_lab, pb, (t == 0) ? 1 : 0, gidx,
            out + (size_t)t * BB,
            out + (size_t)TT * BB + (size_t)t * PP * BB);
    }
}